// Round 7
// baseline (244.643 us; speedup 1.0000x reference)
//
#include <hip/hip_runtime.h>
#include <hip/hip_bf16.h>
#include <stdint.h>

#define DIM    1024
#define HEADS  16
#define DHEAD  64
#define SEQ    2048
#define BATCH  4

typedef unsigned short u16;
typedef __attribute__((ext_vector_type(4))) float f32x4;
typedef __attribute__((ext_vector_type(8))) short bf16x8;

// 0.125 (1/sqrt(64)) * log2(e): scores in log2 domain -> v_exp_f32 is 2^x
#define QSCALE 0.18033688011112042f

__device__ inline u16 f2bf(float f) {
  __hip_bfloat16 h = __float2bfloat16(f);
  return *reinterpret_cast<u16*>(&h);
}

// round-half-up bf16 pair pack: adequate for strictly-positive softmax probs
__device__ inline uint32_t pack_bf16_rhu(float lo, float hi) {
  uint32_t a = __float_as_uint(lo) + 0x8000u;
  uint32_t b = __float_as_uint(hi) + 0x8000u;
  return (b & 0xFFFF0000u) | (a >> 16);
}

__device__ inline void async_load16(const void* g, void* l) {
  __builtin_amdgcn_global_load_lds((const __attribute__((address_space(1))) void*)g,
                                   (__attribute__((address_space(3))) void*)l, 16, 0, 0);
}

// ---------------- Kernel 1: LayerNorm -> bf16 ----------------
__global__ __launch_bounds__(256) void ln_kernel(const float* __restrict__ x,
                                                 const float* __restrict__ w,
                                                 const float* __restrict__ b,
                                                 u16* __restrict__ h) {
  int row = blockIdx.x;
  int t = threadIdx.x;
  const float4* xr = (const float4*)(x + (size_t)row * DIM);
  float4 v = xr[t];
  float s  = v.x + v.y + v.z + v.w;
  float s2 = v.x*v.x + v.y*v.y + v.z*v.z + v.w*v.w;
  for (int m = 1; m < 64; m <<= 1) { s += __shfl_xor(s, m); s2 += __shfl_xor(s2, m); }
  __shared__ float ss[4], ss2[4];
  int wid = t >> 6;
  if ((t & 63) == 0) { ss[wid] = s; ss2[wid] = s2; }
  __syncthreads();
  s  = ss[0] + ss[1] + ss[2] + ss[3];
  s2 = ss2[0] + ss2[1] + ss2[2] + ss2[3];
  float mu  = s * (1.0f / DIM);
  float var = s2 * (1.0f / DIM) - mu * mu;
  float rs  = rsqrtf(var + 1e-5f);
  float4 wv4 = ((const float4*)w)[t];
  float4 bv4 = ((const float4*)b)[t];
  ushort4 o;
  o.x = f2bf((v.x - mu) * rs * wv4.x + bv4.x);
  o.y = f2bf((v.y - mu) * rs * wv4.y + bv4.y);
  o.z = f2bf((v.z - mu) * rs * wv4.z + bv4.z);
  o.w = f2bf((v.w - mu) * rs * wv4.w + bv4.w);
  ((ushort4*)(h + (size_t)row * DIM))[t] = o;
}

// ---------------- Kernel 2: weight transpose -> bf16 (B^T layout) ----------------
__global__ __launch_bounds__(256) void wt_kernel(const float* __restrict__ wq,
                                                 const float* __restrict__ wk,
                                                 const float* __restrict__ wv,
                                                 u16* __restrict__ wt) {
  int mat = blockIdx.z;
  const float* w = (mat == 0) ? wq : ((mat == 1) ? wk : wv);
  __shared__ float tile[32][33];
  int j0 = blockIdx.x * 32, d0 = blockIdx.y * 32;
  int tc = threadIdx.x & 31, tr = threadIdx.x >> 5;
  for (int i = 0; i < 32; i += 8)
    tile[tr + i][tc] = w[(size_t)(d0 + tr + i) * DIM + j0 + tc];
  __syncthreads();
  u16* dst = wt + (size_t)mat * DIM * DIM;
  for (int i = 0; i < 32; i += 8)
    dst[(size_t)(j0 + tr + i) * DIM + d0 + tc] = f2bf(tile[tc][tr + i]);
}

// ---------------- Kernel 3: fused QKV GEMM (M=8192, N=3072, K=1024) ----------------
// 128(M)x256(N) tile, BK=32, DOUBLE-BUFFERED LDS (48 KB): one barrier/iter,
// prefetch issued after the barrier -> the vmcnt drain waits on loads that
// had a full compute iteration to land (kills the m97 2-barrier stall).
// XOR-swizzled LDS image via global source address. Epilogue per-matrix;
// V writes packed 8B (4 consecutive permuted slots).
__global__ __launch_bounds__(256, 2) void gemm_qkv(const u16* __restrict__ A,
                                                   const u16* __restrict__ Bt,
                                                   const float* __restrict__ bq,
                                                   const float* __restrict__ bk,
                                                   const float* __restrict__ bv,
                                                   u16* __restrict__ qo,
                                                   u16* __restrict__ ko,
                                                   u16* __restrict__ vo) {
  __shared__ u16 smem[2 * 12288];   // per buf: lA 128x32 (4096) + lB 256x32 (8192)
  int t = threadIdx.x;
  int bm = blockIdx.x, bn = blockIdx.y;   // x fastest: consecutive blocks share bn
  const u16* Ab = A + (size_t)bm * 128 * DIM;
  const u16* Bb = Bt + (size_t)bn * 256 * DIM;
  int lane = t & 63, w = t >> 6;
  int wm = (w >> 1) * 64, wn = (w & 1) * 128;
  int fr = lane & 15;
  int quad = lane >> 4;
  f32x4 acc[4][8];
  for (int i = 0; i < 4; ++i) for (int j = 0; j < 8; ++j) acc[i][j] = (f32x4)(0.0f);

  // prologue: issue k-tile 0 into buf0
  {
    u16* lA = smem; u16* lB = smem + 4096;
#pragma unroll
    for (int r = 0; r < 2; ++r) {
      int flat = (t + r * 256) * 8;
      int m = flat >> 5, c = (flat >> 3) & 3;
      async_load16(Ab + (size_t)m * DIM + ((c ^ (m & 3)) << 3), lA + flat);
    }
#pragma unroll
    for (int r = 0; r < 4; ++r) {
      int flat = (t + r * 256) * 8;
      int m = flat >> 5, c = (flat >> 3) & 3;
      async_load16(Bb + (size_t)m * DIM + ((c ^ (m & 3)) << 3), lB + flat);
    }
  }

  for (int it = 0; it < 32; ++it) {
    __syncthreads();   // drains buf[it&1]'s loads (issued one full iter ago)
    if (it < 31) {
      int k0 = (it + 1) * 32;
      u16* lA = smem + ((it + 1) & 1) * 12288;
      u16* lB = lA + 4096;
#pragma unroll
      for (int r = 0; r < 2; ++r) {
        int flat = (t + r * 256) * 8;
        int m = flat >> 5, c = (flat >> 3) & 3;
        async_load16(Ab + (size_t)m * DIM + k0 + ((c ^ (m & 3)) << 3), lA + flat);
      }
#pragma unroll
      for (int r = 0; r < 4; ++r) {
        int flat = (t + r * 256) * 8;
        int m = flat >> 5, c = (flat >> 3) & 3;
        async_load16(Bb + (size_t)m * DIM + k0 + ((c ^ (m & 3)) << 3), lB + flat);
      }
    }
    const u16* lA = smem + (it & 1) * 12288;
    const u16* lB = lA + 4096;
    bf16x8 af[4], bfm[8];
#pragma unroll
    for (int i = 0; i < 4; ++i) {
      int m = wm + i * 16 + fr;
      af[i] = *(const bf16x8*)(lA + m * 32 + ((quad ^ (m & 3)) << 3));
    }
#pragma unroll
    for (int j = 0; j < 8; ++j) {
      int m = wn + j * 16 + fr;
      bfm[j] = *(const bf16x8*)(lB + m * 32 + ((quad ^ (m & 3)) << 3));
    }
#pragma unroll
    for (int i = 0; i < 4; ++i)
#pragma unroll
      for (int j = 0; j < 8; ++j)
        acc[i][j] = __builtin_amdgcn_mfma_f32_16x16x32_bf16(af[i], bfm[j], acc[i][j], 0, 0, 0);
  }

  // ---- epilogue: mat is block-uniform (bn>>2) ----
  int matu = bn >> 2;
  int b = bm >> 4;                           // batch (uniform per block)
  int nb = (bm & 15) * 128 + wm + quad * 4;  // + i*16 + r
  if (matu == 0) {
#pragma unroll
    for (int j = 0; j < 8; ++j) {
      int c = (bn * 256 + wn + j * 16 + fr) & 1023;
      float bb = bq[c];
      int head = c >> 6, d = c & 63;
      u16* base = qo + (size_t)(b * HEADS + head) * SEQ * DHEAD + d;
#pragma unroll
      for (int i = 0; i < 4; ++i)
#pragma unroll
        for (int r = 0; r < 4; ++r) {
          int n = nb + i * 16 + r;
          base[(size_t)n * DHEAD] = f2bf((acc[i][j][r] + bb) * QSCALE);
        }
    }
  } else if (matu == 1) {
#pragma unroll
    for (int j = 0; j < 8; ++j) {
      int c = (bn * 256 + wn + j * 16 + fr) & 1023;
      float bb = bk[c];
      int head = c >> 6, d = c & 63;
      u16* base = ko + (size_t)(b * HEADS + head) * SEQ * DHEAD + (d & 7);
      int dc = d >> 3;
#pragma unroll
      for (int i = 0; i < 4; ++i)
#pragma unroll
        for (int r = 0; r < 4; ++r) {
          int n = nb + i * 16 + r;
          // K tile image: [kv][64] rows, 16B chunks xor-swizzled by (kv&7)
          base[(size_t)(n >> 7) * 8192 + (size_t)(n & 127) * 64
               + ((dc ^ (n & 7)) << 3)] = f2bf(acc[i][j][r] + bb);
        }
    }
  } else {
    float bbj[8]; int dj[8]; size_t hbj[8];
#pragma unroll
    for (int j = 0; j < 8; ++j) {
      int c = (bn * 256 + wn + j * 16 + fr) & 1023;
      bbj[j] = bv[c];
      dj[j] = c & 63;
      hbj[j] = (size_t)(b * HEADS + (c >> 6)) * SEQ * DHEAD;
    }
    // V^T image: [d][128] kv-slot permuted to flash's P register order
    // (slot s: kv = 32*(s>>5) + 16*((s>>2)&1) + 4*((s>>3)&3) + (s&3)),
    // 16B chunks xor-swizzled by (d&15). r=0..3 -> 4 consecutive slots
    // within one chunk -> ONE 8B store per (i,j).
#pragma unroll
    for (int i = 0; i < 4; ++i) {
      int n0 = nb + i * 16;                  // n0&3 == 0
      int n127 = n0 & 127; int kv5 = n127 & 31;
      int s0 = (n127 & 96) | ((kv5 & 12) << 1) | ((kv5 & 16) >> 2);
      size_t ro = (size_t)(n0 >> 7) * 8192 + (s0 & 7);
      int sc = s0 >> 3;
#pragma unroll
      for (int j = 0; j < 8; ++j) {
        uint2 pv;
        pv.x = pack_bf16_rhu(acc[i][j][0] + bbj[j], acc[i][j][1] + bbj[j]);
        pv.y = pack_bf16_rhu(acc[i][j][2] + bbj[j], acc[i][j][3] + bbj[j]);
        *(uint2*)(vo + hbj[j] + ro + (size_t)dj[j] * 128 + ((sc ^ (dj[j] & 15)) << 3)) = pv;
      }
    }
  }
}

// ---------------- Kernel 4: flash attention ----------------
// grid (16 q-tiles, 64 bh). Br=Bc=128, 4 waves x 32 q-rows.
// S^T = K*Q^T (softmax lane-local, no online max); P^T built directly in
// registers; V image pre-permuted. DOUBLE-BUFFERED K/V staging (64 KB LDS):
// one barrier/iter, prefetch after barrier -> drain latency hidden.
// Z-trick: T's first MFMA uses a hoisted zero C (no 64 per-iter v_movs).
__global__ __launch_bounds__(256, 2) void flash_attn(const u16* __restrict__ Q,
                                                     const u16* __restrict__ Ksw,
                                                     const u16* __restrict__ Vsw,
                                                     float* __restrict__ out) {
  __shared__ __align__(16) u16 smem[2 * 16384];  // per buf: lK 8192 + lVt 8192

  int t = threadIdx.x;
  int lane = t & 63, w = t >> 6;
  int wrow = w * 32;
  int fr = lane & 15, quad = lane >> 4, fk = quad * 8;
  int qtile = blockIdx.x, bh = blockIdx.y;
  int b = bh >> 4, head = bh & 15;

  const u16* Qb  = Q   + ((size_t)bh * SEQ + qtile * 128) * DHEAD;
  const u16* Kbh = Ksw + (size_t)bh * SEQ * DHEAD;
  const u16* Vbh = Vsw + (size_t)bh * SEQ * DHEAD;

  // stage Q once (into buf0 region), pull B-fragments into registers
  for (int p = 0; p < 4; ++p) {
    int flat = (t + p * 256) * 8;
    async_load16(Qb + flat, smem + flat);
  }
  __syncthreads();
  bf16x8 aq[2][2];
  for (int mi = 0; mi < 2; ++mi)
    for (int ks = 0; ks < 2; ++ks)
      aq[mi][ks] = *(const bf16x8*)(smem + (wrow + mi * 16 + fr) * 64 + ks * 32 + fk);
  __syncthreads();   // all waves done reading Q before buf0 is overwritten

  // prologue: issue K/V tile 0 into buf0
  for (int p = 0; p < 4; ++p) {
    int flat = (t + p * 256) * 8;
    async_load16(Kbh + flat, smem + flat);
    async_load16(Vbh + flat, smem + 8192 + flat);
  }

  const f32x4 Z = (f32x4)(0.0f);
  f32x4 O[4][2];
  for (int nd = 0; nd < 4; ++nd) for (int mi = 0; mi < 2; ++mi) O[nd][mi] = Z;
  float lsum[2] = {0.0f, 0.0f};   // lane-partial; reduced across quads at end

  for (int it = 0; it < 16; ++it) {
    __syncthreads();   // drains buf[it&1]'s loads (issued one full iter ago)
    if (it < 15) {
      u16* dst = smem + ((it + 1) & 1) * 16384;
      const u16* Kb = Kbh + (size_t)(it + 1) * 8192;
      const u16* Vb = Vbh + (size_t)(it + 1) * 8192;
#pragma unroll
      for (int p = 0; p < 4; ++p) {
        int flat = (t + p * 256) * 8;
        async_load16(Kb + flat, dst + flat);
        async_load16(Vb + flat, dst + 8192 + flat);
      }
    }
    const u16* lK  = smem + (it & 1) * 16384;
    const u16* lVt = lK + 8192;

    // ---- T = K * Q^T : rows = k-token, cols = q ----
    f32x4 T[8][2];
#pragma unroll
    for (int ni = 0; ni < 8; ++ni) {
      int kv = ni * 16 + fr;
      int sw = kv & 7;
      bf16x8 kb0 = *(const bf16x8*)(lK + kv * 64 + ((quad ^ sw) << 3));
      bf16x8 kb1 = *(const bf16x8*)(lK + kv * 64 + (((4 + quad) ^ sw) << 3));
      T[ni][0] = __builtin_amdgcn_mfma_f32_16x16x32_bf16(kb0, aq[0][0], Z, 0, 0, 0);
      T[ni][0] = __builtin_amdgcn_mfma_f32_16x16x32_bf16(kb1, aq[0][1], T[ni][0], 0, 0, 0);
      T[ni][1] = __builtin_amdgcn_mfma_f32_16x16x32_bf16(kb0, aq[1][0], Z, 0, 0, 0);
      T[ni][1] = __builtin_amdgcn_mfma_f32_16x16x32_bf16(kb1, aq[1][1], T[ni][1], 0, 0, 0);
    }

    // ---- softmax numerator (base-2, no max shift); pack P into registers ----
    uint32_t pkA[8][2], pkB[8][2];
#pragma unroll
    for (int mi = 0; mi < 2; ++mi) {
      float s = 0.0f;
#pragma unroll
      for (int ni = 0; ni < 8; ++ni) {
        float p0 = __builtin_amdgcn_exp2f(T[ni][mi][0]);
        float p1 = __builtin_amdgcn_exp2f(T[ni][mi][1]);
        float p2 = __builtin_amdgcn_exp2f(T[ni][mi][2]);
        float p3 = __builtin_amdgcn_exp2f(T[ni][mi][3]);
        s += (p0 + p1) + (p2 + p3);
        pkA[ni][mi] = pack_bf16_rhu(p0, p1);
        pkB[ni][mi] = pack_bf16_rhu(p2, p3);
      }
      lsum[mi] += s;
    }

    // ---- O^T += V^T * P^T ; P fragment = direct register concat ----
#pragma unroll
    for (int ks = 0; ks < 4; ++ks) {
      bf16x8 pa[2];
#pragma unroll
      for (int mi = 0; mi < 2; ++mi) {
        union { uint32_t u[4]; bf16x8 v; } cvt;
        cvt.u[0] = pkA[2 * ks][mi];
        cvt.u[1] = pkB[2 * ks][mi];
        cvt.u[2] = pkA[2 * ks + 1][mi];
        cvt.u[3] = pkB[2 * ks + 1][mi];
        pa[mi] = cvt.v;
      }
#pragma unroll
      for (int nd = 0; nd < 4; ++nd) {
        int d = nd * 16 + fr;
        bf16x8 vb = *(const bf16x8*)(lVt + d * 128 + (((ks * 4 + quad) ^ (d & 15)) << 3));
        O[nd][0] = __builtin_amdgcn_mfma_f32_16x16x32_bf16(vb, pa[0], O[nd][0], 0, 0, 0);
        O[nd][1] = __builtin_amdgcn_mfma_f32_16x16x32_bf16(vb, pa[1], O[nd][1], 0, 0, 0);
      }
    }
  }

  // ---- epilogue: reduce lsum across quads, O^T/l -> out, float4 stores ----
  float* ob = out + ((size_t)b * SEQ + qtile * 128) * DIM + head * DHEAD;
#pragma unroll
  for (int mi = 0; mi < 2; ++mi) {
    float ls = lsum[mi];
    ls += __shfl_xor(ls, 16);
    ls += __shfl_xor(ls, 32);
    float inv = 1.0f / ls;
    int q = wrow + mi * 16 + fr;
#pragma unroll
    for (int nd = 0; nd < 4; ++nd) {
      float4 vv;
      vv.x = O[nd][mi][0] * inv;
      vv.y = O[nd][mi][1] * inv;
      vv.z = O[nd][mi][2] * inv;
      vv.w = O[nd][mi][3] * inv;
      *(float4*)(ob + (size_t)q * DIM + nd * 16 + quad * 4) = vv;
    }
  }
}

extern "C" void kernel_launch(void* const* d_in, const int* in_sizes, int n_in,
                              void* d_out, int out_size, void* d_ws, size_t ws_size,
                              hipStream_t stream) {
  const float* x   = (const float*)d_in[0];
  const float* lnw = (const float*)d_in[1];
  const float* lnb = (const float*)d_in[2];
  const float* wq  = (const float*)d_in[3];
  const float* bq  = (const float*)d_in[4];
  const float* wk  = (const float*)d_in[5];
  const float* bk  = (const float*)d_in[6];
  const float* wv  = (const float*)d_in[7];
  const float* bv  = (const float*)d_in[8];
  float* out = (float*)d_out;

  char* ws = (char*)d_ws;
  u16* h  = (u16*)(ws);                 // 8192x1024 bf16   = 16 MB
  u16* wt = (u16*)(ws + 16777216);      // 3072x1024 bf16   =  6 MB
  u16* q  = (u16*)(ws + 23068672);      // [b][h][n][64]    = 16 MB
  u16* k  = (u16*)(ws + 39845888);      // swizzled tiles   = 16 MB
  u16* v  = (u16*)(ws + 56623104);      // swizzled+permuted V^T = 16 MB

  ln_kernel<<<8192, 256, 0, stream>>>(x, lnw, lnb, h);
  wt_kernel<<<dim3(32, 32, 3), 256, 0, stream>>>(wq, wk, wv, wt);
  gemm_qkv<<<dim3(64, 12), 256, 0, stream>>>(h, wt, bq, bk, bv, q, k, v);
  flash_attn<<<dim3(16, 64), 256, 0, stream>>>(q, k, v, out);
}